// Round 1
// baseline (305.016 us; speedup 1.0000x reference)
//
#include <hip/hip_runtime.h>
#include <stdint.h>

// CausalSelfAttention, B=4 N=2048 D=1024, softmax over QUERY axis (axis=1).
// Pipeline: cast->bf16 | QKV gemm | V transpose | S=QK^T/32 (lower tiles, bf16)
//           | column stats (max,sumexp over q>=k) | P=exp(s-M)*rZ in place
//           | O = P @ V  (k-limited per q-tile).

#define BM 128
#define BN 128
#define BK 32

typedef __attribute__((ext_vector_type(8))) short short8;   // 8 bf16 = 4 VGPR
typedef __attribute__((ext_vector_type(4))) float f32x4;

static __device__ __forceinline__ ushort f2bf(float f) {
  union { float f; uint32_t u; } v; v.f = f;
  uint32_t r = v.u + 0x7FFFu + ((v.u >> 16) & 1u);   // RNE
  return (ushort)(r >> 16);
}
static __device__ __forceinline__ float bf2f(ushort u) {
  union { uint32_t u; float f; } v; v.u = ((uint32_t)u) << 16;
  return v.f;
}

static __device__ __forceinline__ void gload_lds16(const ushort* g, ushort* l) {
  // 16B/lane direct global->LDS; LDS dest is wave-uniform base + lane*16,
  // our seg = it*256+tid is lane-contiguous within each wave, so linear dest is correct.
  __builtin_amdgcn_global_load_lds(
      (const __attribute__((address_space(1))) void*)g,
      (__attribute__((address_space(3))) void*)l, 16, 0, 0);
}

// ---------------- casts ----------------
__global__ void cast_f32_bf16(const float* __restrict__ in, ushort* __restrict__ out, int n4) {
  int i = blockIdx.x * blockDim.x + threadIdx.x;
  if (i >= n4) return;
  float4 v = ((const float4*)in)[i];
  ushort4 o;
  o.x = f2bf(v.x); o.y = f2bf(v.y); o.z = f2bf(v.z); o.w = f2bf(v.w);
  ((ushort4*)out)[i] = o;
}

// ---------------- bf16 GEMM, C = alpha * A @ Bt^T ----------------
// A: [M][K] bf16 (K contiguous). Bt: [Nn][K] bf16 (K contiguous). C row-major [M][Nn].
// CMODE: 0 = bf16 C, 1 = f32 C.
// KMODE: 0 = full K; 1 = kEnd = min(K, bm0+BM)  (causal PV);
//        2 = skip blocks with bn0 > bm0 (causal S), full K.
template <int CMODE, int KMODE>
__global__ __launch_bounds__(256) void gemm_bt(
    const ushort* __restrict__ A, const ushort* __restrict__ Bt, void* __restrict__ C,
    int M, int Nn, int K, long sA, long sB, long sC, float alpha)
{
  const int bm0 = blockIdx.x * BM;
  const int bn0 = blockIdx.y * BN;
  if (KMODE == 2 && bn0 > bm0) return;

  const ushort* Ab = A + (long)blockIdx.z * sA;
  const ushort* Bb = Bt + (long)blockIdx.z * sB;

  int kEnd = K;
  if (KMODE == 1) { int ke = bm0 + BM; kEnd = ke < K ? ke : K; }

  __shared__ ushort As[BM * BK];   // [128][32] bf16, 8KB
  __shared__ ushort Bs[BN * BK];

  const int tid  = threadIdx.x;
  const int lane = tid & 63;
  const int wave = tid >> 6;           // 4 waves, 2x2 of 64x64
  const int wm   = (wave >> 1) * 64;
  const int wn   = (wave & 1) * 64;
  const int fr   = lane & 15;          // fragment row/col
  const int fg   = lane >> 4;          // k-group (8 contiguous k)

  f32x4 acc[4][4];
#pragma unroll
  for (int i = 0; i < 4; ++i)
#pragma unroll
    for (int j = 0; j < 4; ++j) acc[i][j] = (f32x4){0.f, 0.f, 0.f, 0.f};

  for (int k0 = 0; k0 < kEnd; k0 += BK) {
    // stage 128x32 bf16 A and B tiles: 512 x 16B segments each, 2 per thread
#pragma unroll
    for (int it = 0; it < 2; ++it) {
      int s = it * 256 + tid;
      int row = s >> 2;
      int col = (s & 3) * 8;
      gload_lds16(Ab + (long)(bm0 + row) * K + (k0 + col), &As[s * 8]);
      gload_lds16(Bb + (long)(bn0 + row) * K + (k0 + col), &Bs[s * 8]);
    }
    __syncthreads();   // compiler drains vmcnt before s_barrier

    short8 af[4], bfg[4];
#pragma unroll
    for (int i = 0; i < 4; ++i)
      af[i] = *(const short8*)&As[(wm + i * 16 + fr) * BK + fg * 8];
#pragma unroll
    for (int j = 0; j < 4; ++j)
      bfg[j] = *(const short8*)&Bs[(wn + j * 16 + fr) * BK + fg * 8];
#pragma unroll
    for (int i = 0; i < 4; ++i)
#pragma unroll
      for (int j = 0; j < 4; ++j)
        acc[i][j] = __builtin_amdgcn_mfma_f32_16x16x32_bf16(af[i], bfg[j], acc[i][j], 0, 0, 0);
    __syncthreads();
  }

  // epilogue: C/D map (m89-verified): col = lane&15, row = (lane>>4)*4 + r
  if (CMODE == 0) {
    ushort* Cb = (ushort*)C + (long)blockIdx.z * sC;
#pragma unroll
    for (int i = 0; i < 4; ++i)
#pragma unroll
      for (int j = 0; j < 4; ++j)
#pragma unroll
        for (int r = 0; r < 4; ++r) {
          int row = bm0 + wm + i * 16 + fg * 4 + r;
          int col = bn0 + wn + j * 16 + fr;
          Cb[(long)row * Nn + col] = f2bf(acc[i][j][r] * alpha);
        }
  } else {
    float* Cb = (float*)C + (long)blockIdx.z * sC;
#pragma unroll
    for (int i = 0; i < 4; ++i)
#pragma unroll
      for (int j = 0; j < 4; ++j)
#pragma unroll
        for (int r = 0; r < 4; ++r) {
          int row = bm0 + wm + i * 16 + fg * 4 + r;
          int col = bn0 + wn + j * 16 + fr;
          Cb[(long)row * Nn + col] = acc[i][j][r] * alpha;
        }
  }
}

// ---------------- bf16 transpose: in [z][rows][cols] -> out [z][cols][rows] ----------------
__global__ void transpose_bf16(const ushort* __restrict__ in, ushort* __restrict__ out,
                               int rows, int cols) {
  __shared__ ushort t[64][65];
  int c0 = blockIdx.x * 64, r0 = blockIdx.y * 64;
  long base = (long)blockIdx.z * rows * cols;
  int tid = threadIdx.x;
#pragma unroll
  for (int i = 0; i < 16; ++i) {
    int idx = i * 256 + tid, r = idx >> 6, c = idx & 63;
    t[r][c] = in[base + (long)(r0 + r) * cols + c0 + c];
  }
  __syncthreads();
#pragma unroll
  for (int i = 0; i < 16; ++i) {
    int idx = i * 256 + tid, r = idx >> 6, c = idx & 63;
    out[base + (long)(c0 + r) * rows + r0 + c] = t[c][r];
  }
}

// ---------------- column softmax stats over q axis ----------------
#define QCH 256
__global__ void colstats_partial(const ushort* __restrict__ S, float* __restrict__ pM,
                                 float* __restrict__ pZ, int Nq) {
  int k = blockIdx.x * 256 + threadIdx.x;
  int qc = blockIdx.y;
  int b = blockIdx.z;
  const ushort* Sb = S + (long)b * Nq * Nq;
  int q0 = qc * QCH, q1 = q0 + QCH;
  int qs = q0 > k ? q0 : k;            // causal: only q >= k valid
  float m = -3.0e38f, z = 0.f;
  for (int q = qs; q < q1; ++q) {
    float s = bf2f(Sb[(long)q * Nq + k]);
    float nm = fmaxf(m, s);
    z = z * __expf(m - nm) + __expf(s - nm);
    m = nm;
  }
  long o = (long)(b * 8 + qc) * Nq + k;
  pM[o] = m; pZ[o] = z;
}

__global__ void colstats_combine(const float* __restrict__ pM, const float* __restrict__ pZ,
                                 float2* __restrict__ Mz, int Nq) {
  int idx = blockIdx.x * 256 + threadIdx.x;   // b*Nq + k
  int b = idx / Nq, k = idx - b * Nq;
  float M = -3.0e38f;
  for (int c = 0; c < 8; ++c) M = fmaxf(M, pM[(long)(b * 8 + c) * Nq + k]);
  float Z = 0.f;
  for (int c = 0; c < 8; ++c) {
    long o = (long)(b * 8 + c) * Nq + k;
    Z += pZ[o] * __expf(pM[o] - M);
  }
  Mz[idx] = make_float2(M, 1.0f / Z);
}

// ---------------- P = exp(s - M[k]) * rZ[k] (0 where k > q), in place ----------------
__global__ void make_p(ushort* __restrict__ S, const float2* __restrict__ Mz, int Nq) {
  long t = (long)blockIdx.x * 256 + threadIdx.x;   // covers B*Nq*Nq/8
  int kb = (int)(t % (Nq / 8)) * 8;
  long row = t / (Nq / 8);                          // b*Nq + q
  int q = (int)(row % Nq);
  int b = (int)(row / Nq);
  ushort* Sp = S + row * Nq + kb;
  union { uint4 v; ushort u[8]; } d, o;
  d.v = *(const uint4*)Sp;
  const float2* mz = Mz + (long)b * Nq + kb;
#pragma unroll
  for (int j = 0; j < 8; ++j) {
    float2 m = mz[j];
    float p = (q >= kb + j) ? __expf(bf2f(d.u[j]) - m.x) * m.y : 0.f;
    o.u[j] = f2bf(p);
  }
  *(uint4*)Sp = o.v;
}

// ---------------- launch ----------------
extern "C" void kernel_launch(void* const* d_in, const int* in_sizes, int n_in,
                              void* d_out, int out_size, void* d_ws, size_t ws_size,
                              hipStream_t stream) {
  const float* x  = (const float*)d_in[0];
  const float* Wq = (const float*)d_in[1];
  const float* Wk = (const float*)d_in[2];
  const float* Wv = (const float*)d_in[3];
  float* out = (float*)d_out;

  const int B = 4, N = 2048, D = 1024;
  const long BND = (long)B * N * D;      // 8388608

  char* ws = (char*)d_ws;
  // xb region is dead after the projection GEMM; Vt aliases it (exactly 16MB each).
  ushort* xb  = (ushort*)ws;                         // [B*N][D] bf16, 16MB
  ushort* Vt  = xb;                                  // [B][D][N] bf16, aliases xb
  ushort* Wb  = xb + BND;                            // [3][D][D] bf16, 6MB
  ushort* QKV = Wb + 3L * D * D;                     // [3][B*N][D] bf16, 48MB
  ushort* Qb  = QKV;
  ushort* Kb  = QKV + BND;
  ushort* Vb  = QKV + 2 * BND;
  ushort* S   = QKV + 3 * BND;                       // [B][N][N] bf16, 32MB
  float*  pM  = (float*)(S + (long)B * N * N);       // [B][8][N]
  float*  pZ  = pM + (long)B * 8 * N;
  float2* Mz  = (float2*)(pZ + (long)B * 8 * N);     // [B][N] (M, 1/Z)

  // K0: casts
  cast_f32_bf16<<<(int)(BND / 4 / 256), 256, 0, stream>>>(x, xb, (int)(BND / 4));
  cast_f32_bf16<<<(D * D / 4) / 256, 256, 0, stream>>>(Wq, Wb, D * D / 4);
  cast_f32_bf16<<<(D * D / 4) / 256, 256, 0, stream>>>(Wk, Wb + (long)D * D, D * D / 4);
  cast_f32_bf16<<<(D * D / 4) / 256, 256, 0, stream>>>(Wv, Wb + 2L * D * D, D * D / 4);

  // K1: Q/K/V projections (z = 0,1,2 selects W and output chunk)
  {
    dim3 g(B * N / BM, D / BN, 3);
    gemm_bt<0, 0><<<g, 256, 0, stream>>>(xb, Wb, (void*)QKV, B * N, D, D,
                                         0L, (long)D * D, BND, 1.0f);
  }

  // K2: V -> V^T  (xb now dead; Vt aliases it)
  {
    dim3 g(D / 64, N / 64, B);
    transpose_bf16<<<g, 256, 0, stream>>>(Vb, Vt, N, D);
  }

  // K3: S = Q K^T / 32, lower-triangular tiles only, bf16
  {
    dim3 g(N / BM, N / BN, B);
    gemm_bt<0, 2><<<g, 256, 0, stream>>>(Qb, Kb, (void*)S, N, N, D,
                                         (long)N * D, (long)N * D, (long)N * N, 0.03125f);
  }

  // K3b: column (query-axis) softmax stats
  {
    dim3 g(N / 256, 8, B);
    colstats_partial<<<g, 256, 0, stream>>>(S, pM, pZ, N);
    colstats_combine<<<(B * N) / 256, 256, 0, stream>>>(pM, pZ, Mz, N);
  }

  // K4: P in place over full matrix (zeros above diagonal)
  make_p<<<(int)((long)B * N * N / 8 / 256), 256, 0, stream>>>(S, Mz, N);

  // K5: O = P @ V   (A = P [q][k], Bt = Vt [d][k], kEnd = (tq+1)*128)
  {
    dim3 g(N / BM, D / BN, B);
    gemm_bt<1, 1><<<g, 256, 0, stream>>>(S, Vt, (void*)out, N, D, N,
                                         (long)N * N, (long)D * N, (long)N * D, 1.0f);
  }
}

// Round 2
// 277.740 us; speedup vs baseline: 1.0982x; 1.0982x over previous
//
#include <hip/hip_runtime.h>
#include <stdint.h>

// CausalSelfAttention, B=4 N=2048 D=1024, softmax over QUERY axis (axis=1).
// Pipeline: cast->bf16 | QKV gemm (256^2 8-phase) | V transpose
//           | S=QK^T/32 (256^2 8-phase, lower tiles, bf16)
//           | column stats (max,sumexp over q>=k) | P=exp(s-M)*rZ in place
//           | O = P @ V (old 128^2 gemm, k-limited per q-tile).

#define BM 128
#define BN 128
#define BK 32

typedef __attribute__((ext_vector_type(8))) short short8;   // 8 bf16 = 4 VGPR
typedef __attribute__((ext_vector_type(4))) float f32x4;

static __device__ __forceinline__ ushort f2bf(float f) {
  union { float f; uint32_t u; } v; v.f = f;
  uint32_t r = v.u + 0x7FFFu + ((v.u >> 16) & 1u);   // RNE
  return (ushort)(r >> 16);
}
static __device__ __forceinline__ float bf2f(ushort u) {
  union { uint32_t u; float f; } v; v.u = ((uint32_t)u) << 16;
  return v.f;
}

static __device__ __forceinline__ void gload_lds16(const ushort* g, ushort* l) {
  __builtin_amdgcn_global_load_lds(
      (const __attribute__((address_space(1))) void*)g,
      (__attribute__((address_space(3))) void*)l, 16, 0, 0);
}

#define SBAR()   __builtin_amdgcn_s_barrier()
#define SCHED0() __builtin_amdgcn_sched_barrier(0)
#define WAITL0() do { asm volatile("s_waitcnt lgkmcnt(0)" ::: "memory"); SCHED0(); } while (0)
#define WAITV8() asm volatile("s_waitcnt vmcnt(8)" ::: "memory")
#define WAITV4() asm volatile("s_waitcnt vmcnt(4)" ::: "memory")
#define WAITV0() asm volatile("s_waitcnt vmcnt(0)" ::: "memory")

// ---------------- casts ----------------
__global__ void cast_f32_bf16(const float* __restrict__ in, ushort* __restrict__ out, int n4) {
  int i = blockIdx.x * blockDim.x + threadIdx.x;
  if (i >= n4) return;
  float4 v = ((const float4*)in)[i];
  ushort4 o;
  o.x = f2bf(v.x); o.y = f2bf(v.y); o.z = f2bf(v.z); o.w = f2bf(v.w);
  ((ushort4*)out)[i] = o;
}

// =====================================================================
// 256x256 / BK=64 / 8-wave 8-phase GEMM (T2 swizzle + T3/T4 counted vmcnt
// + T5 setprio).  C(bf16) = alpha * A @ Bt^T.  A:[M][K], Bt:[Nn][K], K%128==0.
// KMODE: 0 = full grid; 2 = skip blocks with bn0 > bm0 (causal S).
// LDS per buffer: A[kh][256][32] @ 0/16K, B[kh][256][32] @ 32K/48K; 2 buffers.
// Swizzle: 16B-chunk c at (row) stored at c ^ ((row>>1)&3)  (involution,
// applied on pre-swizzled global source AND on ds_read address).
// =====================================================================
template <int KMODE>
__global__ __launch_bounds__(512, 2) void gemm256(
    const ushort* __restrict__ A, const ushort* __restrict__ Bt, ushort* __restrict__ C,
    int M, int Nn, int K, long sA, long sB, long sC, float alpha)
{
  const int bm0 = blockIdx.x * 256;
  const int bn0 = blockIdx.y * 256;
  if (KMODE == 2 && bn0 > bm0) return;

  const ushort* Ab = A + (long)blockIdx.z * sA;
  const ushort* Bb = Bt + (long)blockIdx.z * sB;

  __shared__ uint4 lds_v[131072 / 16];
  char* lds = (char*)lds_v;

  const int tid  = threadIdx.x;
  const int lane = tid & 63;
  const int wave = tid >> 6;       // 8 waves: 2(M) x 4(N)
  const int wr   = wave >> 2;      // 0..1 -> rows wr*128..+128
  const int wc   = wave & 3;       // 0..3 -> cols wc*64..+64
  const int fr   = lane & 15;
  const int fg   = lane >> 4;      // 16B chunk within 32-k slab

  const int nk = K >> 6;           // K-tiles of 64

  f32x4 acc[8][4];
#pragma unroll
  for (int i = 0; i < 8; ++i)
#pragma unroll
    for (int j = 0; j < 4; ++j) acc[i][j] = (f32x4){0.f, 0.f, 0.f, 0.f};

  // stage one half-tile (16KB): h = 0:A-kh0, 1:B-kh0, 2:A-kh1, 3:B-kh1
  auto STAGE = [&](int tt, int h) {
    if (tt >= nk) return;
    const int isB = h & 1, kh = h >> 1;
    const ushort* G = isB ? Bb : Ab;
    const int r0 = isB ? bn0 : bm0;
    char* slab = lds + ((tt & 1) * 65536 + isB * 32768 + kh * 16384);
#pragma unroll
    for (int u = 0; u < 2; ++u) {
      int s = u * 512 + tid;
      int row = s >> 2;
      int cc = (s & 3) ^ ((row >> 1) & 3);          // pre-swizzled source chunk
      gload_lds16(G + (long)(r0 + row) * K + tt * 64 + kh * 32 + cc * 8,
                  (ushort*)(slab + s * 16));
    }
  };

  short8 a[4], b[4];
  auto READA = [&](int cur, int kh, int mh) {
    char* slab = lds + (cur * 65536 + kh * 16384);
#pragma unroll
    for (int i = 0; i < 4; ++i) {
      int row = wr * 128 + (mh * 4 + i) * 16 + fr;
      int cc = fg ^ ((row >> 1) & 3);
      a[i] = *(const short8*)(slab + row * 64 + cc * 16);
    }
  };
  auto READB = [&](int cur, int kh) {
    char* slab = lds + (cur * 65536 + 32768 + kh * 16384);
#pragma unroll
    for (int j = 0; j < 4; ++j) {
      int row = wc * 64 + j * 16 + fr;
      int cc = fg ^ ((row >> 1) & 3);
      b[j] = *(const short8*)(slab + row * 64 + cc * 16);
    }
  };
  auto MM = [&](int mh) {
#pragma unroll
    for (int i = 0; i < 4; ++i)
#pragma unroll
      for (int j = 0; j < 4; ++j)
        acc[mh * 4 + i][j] =
            __builtin_amdgcn_mfma_f32_16x16x32_bf16(a[i], b[j], acc[mh * 4 + i][j], 0, 0, 0);
  };

  // prologue: tile0 all 4 halves + tile1 h0,h1  (12 loads/thread)
  STAGE(0, 0); STAGE(0, 1); STAGE(0, 2); STAGE(0, 3);
  STAGE(1, 0); STAGE(1, 1);
  WAITV8();            // oldest 4 (t0.h0,h1) landed
  SBAR();

  for (int t = 0; t < nk; ++t) {
    const int cur = t & 1;
    // ---- ph0: kh0, m-half0 ----
    READA(cur, 0, 0); READB(cur, 0);
    STAGE(t + 1, 2);
    SBAR(); WAITL0();
    __builtin_amdgcn_s_setprio(1); MM(0); __builtin_amdgcn_s_setprio(0);
    SBAR();
    // ---- ph1: kh0, m-half1 (reuse b) ----
    READA(cur, 0, 1);
    STAGE(t + 1, 3);
    if (t + 1 < nk) { WAITV8(); } else { WAITV0(); }   // guards t.h2,h3
    SBAR(); WAITL0();
    __builtin_amdgcn_s_setprio(1); MM(1); __builtin_amdgcn_s_setprio(0);
    SBAR();
    // ---- ph2: kh1, m-half0 ----
    READA(cur, 1, 0); READB(cur, 1);
    STAGE(t + 2, 0);
    SBAR(); WAITL0();
    __builtin_amdgcn_s_setprio(1); MM(0); __builtin_amdgcn_s_setprio(0);
    SBAR();
    // ---- ph3: kh1, m-half1 ----
    READA(cur, 1, 1);
    STAGE(t + 2, 1);
    if (t + 2 < nk)      { WAITV8(); }                 // guards t+1.h0,h1
    else if (t + 1 < nk) { WAITV4(); }
    SBAR(); WAITL0();
    __builtin_amdgcn_s_setprio(1); MM(1); __builtin_amdgcn_s_setprio(0);
    SBAR();
  }

  // epilogue: C/D map: col = lane&15, row = (lane>>4)*4 + r
  ushort* Cb = C + (long)blockIdx.z * sC;
#pragma unroll
  for (int mi = 0; mi < 8; ++mi)
#pragma unroll
    for (int j = 0; j < 4; ++j)
#pragma unroll
      for (int r = 0; r < 4; ++r) {
        int row = bm0 + wr * 128 + mi * 16 + fg * 4 + r;
        int col = bn0 + wc * 64 + j * 16 + fr;
        Cb[(long)row * Nn + col] = f2bf(acc[mi][j][r] * alpha);
      }
}

// ---------------- old 128^2 bf16 GEMM (kept for PV with causal k-limit) ----------------
// CMODE: 0 = bf16 C, 1 = f32 C.  KMODE: 1 = kEnd = min(K, bm0+BM).
template <int CMODE, int KMODE>
__global__ __launch_bounds__(256) void gemm_bt(
    const ushort* __restrict__ A, const ushort* __restrict__ Bt, void* __restrict__ C,
    int M, int Nn, int K, long sA, long sB, long sC, float alpha)
{
  const int bm0 = blockIdx.x * BM;
  const int bn0 = blockIdx.y * BN;
  if (KMODE == 2 && bn0 > bm0) return;

  const ushort* Ab = A + (long)blockIdx.z * sA;
  const ushort* Bb = Bt + (long)blockIdx.z * sB;

  int kEnd = K;
  if (KMODE == 1) { int ke = bm0 + BM; kEnd = ke < K ? ke : K; }

  __shared__ ushort As[BM * BK];
  __shared__ ushort Bs[BN * BK];

  const int tid  = threadIdx.x;
  const int lane = tid & 63;
  const int wave = tid >> 6;
  const int wm   = (wave >> 1) * 64;
  const int wn   = (wave & 1) * 64;
  const int fr   = lane & 15;
  const int fg   = lane >> 4;

  f32x4 acc[4][4];
#pragma unroll
  for (int i = 0; i < 4; ++i)
#pragma unroll
    for (int j = 0; j < 4; ++j) acc[i][j] = (f32x4){0.f, 0.f, 0.f, 0.f};

  for (int k0 = 0; k0 < kEnd; k0 += BK) {
#pragma unroll
    for (int it = 0; it < 2; ++it) {
      int s = it * 256 + tid;
      int row = s >> 2;
      int col = (s & 3) * 8;
      gload_lds16(Ab + (long)(bm0 + row) * K + (k0 + col), &As[s * 8]);
      gload_lds16(Bb + (long)(bn0 + row) * K + (k0 + col), &Bs[s * 8]);
    }
    __syncthreads();

    short8 af[4], bfg[4];
#pragma unroll
    for (int i = 0; i < 4; ++i)
      af[i] = *(const short8*)&As[(wm + i * 16 + fr) * BK + fg * 8];
#pragma unroll
    for (int j = 0; j < 4; ++j)
      bfg[j] = *(const short8*)&Bs[(wn + j * 16 + fr) * BK + fg * 8];
#pragma unroll
    for (int i = 0; i < 4; ++i)
#pragma unroll
      for (int j = 0; j < 4; ++j)
        acc[i][j] = __builtin_amdgcn_mfma_f32_16x16x32_bf16(af[i], bfg[j], acc[i][j], 0, 0, 0);
    __syncthreads();
  }

  if (CMODE == 0) {
    ushort* Cb = (ushort*)C + (long)blockIdx.z * sC;
#pragma unroll
    for (int i = 0; i < 4; ++i)
#pragma unroll
      for (int j = 0; j < 4; ++j)
#pragma unroll
        for (int r = 0; r < 4; ++r) {
          int row = bm0 + wm + i * 16 + fg * 4 + r;
          int col = bn0 + wn + j * 16 + fr;
          Cb[(long)row * Nn + col] = f2bf(acc[i][j][r] * alpha);
        }
  } else {
    float* Cb = (float*)C + (long)blockIdx.z * sC;
#pragma unroll
    for (int i = 0; i < 4; ++i)
#pragma unroll
      for (int j = 0; j < 4; ++j)
#pragma unroll
        for (int r = 0; r < 4; ++r) {
          int row = bm0 + wm + i * 16 + fg * 4 + r;
          int col = bn0 + wn + j * 16 + fr;
          Cb[(long)row * Nn + col] = acc[i][j][r] * alpha;
        }
  }
}

// ---------------- bf16 transpose ----------------
__global__ void transpose_bf16(const ushort* __restrict__ in, ushort* __restrict__ out,
                               int rows, int cols) {
  __shared__ ushort t[64][65];
  int c0 = blockIdx.x * 64, r0 = blockIdx.y * 64;
  long base = (long)blockIdx.z * rows * cols;
  int tid = threadIdx.x;
#pragma unroll
  for (int i = 0; i < 16; ++i) {
    int idx = i * 256 + tid, r = idx >> 6, c = idx & 63;
    t[r][c] = in[base + (long)(r0 + r) * cols + c0 + c];
  }
  __syncthreads();
#pragma unroll
  for (int i = 0; i < 16; ++i) {
    int idx = i * 256 + tid, r = idx >> 6, c = idx & 63;
    out[base + (long)(c0 + r) * rows + r0 + c] = t[c][r];
  }
}

// ---------------- column softmax stats over q axis ----------------
#define QCH 256
__global__ void colstats_partial(const ushort* __restrict__ S, float* __restrict__ pM,
                                 float* __restrict__ pZ, int Nq) {
  int k = blockIdx.x * 256 + threadIdx.x;
  int qc = blockIdx.y;
  int b = blockIdx.z;
  const ushort* Sb = S + (long)b * Nq * Nq;
  int q0 = qc * QCH, q1 = q0 + QCH;
  int qs = q0 > k ? q0 : k;
  float m = -3.0e38f, z = 0.f;
  for (int q = qs; q < q1; ++q) {
    float s = bf2f(Sb[(long)q * Nq + k]);
    float nm = fmaxf(m, s);
    z = z * __expf(m - nm) + __expf(s - nm);
    m = nm;
  }
  long o = (long)(b * 8 + qc) * Nq + k;
  pM[o] = m; pZ[o] = z;
}

__global__ void colstats_combine(const float* __restrict__ pM, const float* __restrict__ pZ,
                                 float2* __restrict__ Mz, int Nq) {
  int idx = blockIdx.x * 256 + threadIdx.x;
  int b = idx / Nq, k = idx - b * Nq;
  float M = -3.0e38f;
  for (int c = 0; c < 8; ++c) M = fmaxf(M, pM[(long)(b * 8 + c) * Nq + k]);
  float Z = 0.f;
  for (int c = 0; c < 8; ++c) {
    long o = (long)(b * 8 + c) * Nq + k;
    Z += pZ[o] * __expf(pM[o] - M);
  }
  Mz[idx] = make_float2(M, 1.0f / Z);
}

// ---------------- P = exp(s - M[k]) * rZ[k] (0 where k > q), in place ----------------
__global__ void make_p(ushort* __restrict__ S, const float2* __restrict__ Mz, int Nq) {
  long t = (long)blockIdx.x * 256 + threadIdx.x;
  int kb = (int)(t % (Nq / 8)) * 8;
  long row = t / (Nq / 8);
  int q = (int)(row % Nq);
  int b = (int)(row / Nq);
  ushort* Sp = S + row * Nq + kb;
  union { uint4 v; ushort u[8]; } d, o;
  d.v = *(const uint4*)Sp;
  const float2* mz = Mz + (long)b * Nq + kb;
#pragma unroll
  for (int j = 0; j < 8; ++j) {
    float2 m = mz[j];
    float p = (q >= kb + j) ? __expf(bf2f(d.u[j]) - m.x) * m.y : 0.f;
    o.u[j] = f2bf(p);
  }
  *(uint4*)Sp = o.v;
}

// ---------------- launch ----------------
extern "C" void kernel_launch(void* const* d_in, const int* in_sizes, int n_in,
                              void* d_out, int out_size, void* d_ws, size_t ws_size,
                              hipStream_t stream) {
  const float* x  = (const float*)d_in[0];
  const float* Wq = (const float*)d_in[1];
  const float* Wk = (const float*)d_in[2];
  const float* Wv = (const float*)d_in[3];
  float* out = (float*)d_out;

  const int B = 4, N = 2048, D = 1024;
  const long BND = (long)B * N * D;

  char* ws = (char*)d_ws;
  ushort* xb  = (ushort*)ws;                         // [B*N][D] bf16, 16MB
  ushort* Vt  = xb;                                  // aliases xb (dead after K1/K2 order below)
  ushort* Wb  = xb + BND;                            // [3][D][D] bf16
  ushort* QKV = Wb + 3L * D * D;                     // [3][B*N][D]
  ushort* Qb  = QKV;
  ushort* Kb  = QKV + BND;
  ushort* Vb  = QKV + 2 * BND;
  ushort* S   = QKV + 3 * BND;                       // [B][N][N] bf16
  float*  pM  = (float*)(S + (long)B * N * N);
  float*  pZ  = pM + (long)B * 8 * N;
  float2* Mz  = (float2*)(pZ + (long)B * 8 * N);

  // K0: casts
  cast_f32_bf16<<<(int)(BND / 4 / 256), 256, 0, stream>>>(x, xb, (int)(BND / 4));
  cast_f32_bf16<<<(D * D / 4) / 256, 256, 0, stream>>>(Wq, Wb, D * D / 4);
  cast_f32_bf16<<<(D * D / 4) / 256, 256, 0, stream>>>(Wk, Wb + (long)D * D, D * D / 4);
  cast_f32_bf16<<<(D * D / 4) / 256, 256, 0, stream>>>(Wv, Wb + 2L * D * D, D * D / 4);

  // K1: Q/K/V projections, 256^2 8-phase
  {
    dim3 g(B * N / 256, D / 256, 3);
    gemm256<0><<<g, 512, 0, stream>>>(xb, Wb, QKV, B * N, D, D,
                                      0L, (long)D * D, BND, 1.0f);
  }

  // K2: V -> V^T (xb dead now)
  {
    dim3 g(D / 64, N / 64, B);
    transpose_bf16<<<g, 256, 0, stream>>>(Vb, Vt, N, D);
  }

  // K3: S = Q K^T / 32, lower tiles only, 256^2 8-phase
  {
    dim3 g(N / 256, N / 256, B);
    gemm256<2><<<g, 512, 0, stream>>>(Qb, Kb, S, N, N, D,
                                      (long)N * D, (long)N * D, (long)N * N, 0.03125f);
  }

  // K3b: column (query-axis) softmax stats
  {
    dim3 g(N / 256, 8, B);
    colstats_partial<<<g, 256, 0, stream>>>(S, pM, pZ, N);
    colstats_combine<<<(B * N) / 256, 256, 0, stream>>>(pM, pZ, Mz, N);
  }

  // K4: P in place (zeros above diagonal)
  make_p<<<(int)((long)B * N * N / 8 / 256), 256, 0, stream>>>(S, Mz, N);

  // K5: O = P @ V (old kernel, kEnd = bm0+128 causal limit)
  {
    dim3 g(N / BM, D / BN, B);
    gemm_bt<1, 1><<<g, 256, 0, stream>>>(S, Vt, (void*)out, N, D, N,
                                         (long)N * N, (long)D * N, (long)N * D, 1.0f);
  }
}

// Round 4
// 252.014 us; speedup vs baseline: 1.2103x; 1.1021x over previous
//
#include <hip/hip_runtime.h>
#include <stdint.h>

// CausalSelfAttention, B=4 N=2048 D=1024, softmax over QUERY axis (axis=1).
// Pipeline: cast->bf16 | QKV gemm (256^2 8-phase) | V transpose
//           | S=QK^T/32 (256^2 8-phase, lower tiles, bf16)
//           | column stats (ILP 8-col/thread, QCH=32) | P=exp(s-M)*rZ (PV-read set only)
//           | O = P @ V (128^2 gemm, k-limited per q-tile).

#define BM 128
#define BN 128
#define BK 32

#define QCH 32
#define NQC 64   // N / QCH

typedef __attribute__((ext_vector_type(8))) short short8;   // 8 bf16 = 4 VGPR
typedef __attribute__((ext_vector_type(4))) float f32x4;

static __device__ __forceinline__ ushort f2bf(float f) {
  union { float f; uint32_t u; } v; v.f = f;
  uint32_t r = v.u + 0x7FFFu + ((v.u >> 16) & 1u);   // RNE
  return (ushort)(r >> 16);
}
static __device__ __forceinline__ float bf2f(ushort u) {
  union { uint32_t u; float f; } v; v.u = ((uint32_t)u) << 16;
  return v.f;
}

static __device__ __forceinline__ void gload_lds16(const ushort* g, ushort* l) {
  __builtin_amdgcn_global_load_lds(
      (const __attribute__((address_space(1))) void*)g,
      (__attribute__((address_space(3))) void*)l, 16, 0, 0);
}

#define SBAR()   __builtin_amdgcn_s_barrier()
#define SCHED0() __builtin_amdgcn_sched_barrier(0)
#define WAITL0() do { asm volatile("s_waitcnt lgkmcnt(0)" ::: "memory"); SCHED0(); } while (0)
#define WAITV8() asm volatile("s_waitcnt vmcnt(8)" ::: "memory")
#define WAITV4() asm volatile("s_waitcnt vmcnt(4)" ::: "memory")
#define WAITV0() asm volatile("s_waitcnt vmcnt(0)" ::: "memory")

// ---------------- casts ----------------
__global__ void cast_f32_bf16(const float* __restrict__ in, ushort* __restrict__ out, int n4) {
  int i = blockIdx.x * blockDim.x + threadIdx.x;
  if (i >= n4) return;
  float4 v = ((const float4*)in)[i];
  ushort4 o;
  o.x = f2bf(v.x); o.y = f2bf(v.y); o.z = f2bf(v.z); o.w = f2bf(v.w);
  ((ushort4*)out)[i] = o;
}

// =====================================================================
// 256x256 / BK=64 / 8-wave 8-phase GEMM (T2 swizzle + T3/T4 counted vmcnt
// + T5 setprio).  C(bf16) = alpha * A @ Bt^T.  A:[M][K], Bt:[Nn][K], K%128==0.
// KMODE: 0 = full grid; 2 = skip blocks with bn0 > bm0 (causal S).
// =====================================================================
template <int KMODE>
__global__ __launch_bounds__(512, 2) void gemm256(
    const ushort* __restrict__ A, const ushort* __restrict__ Bt, ushort* __restrict__ C,
    int M, int Nn, int K, long sA, long sB, long sC, float alpha)
{
  const int bm0 = blockIdx.x * 256;
  const int bn0 = blockIdx.y * 256;
  if (KMODE == 2 && bn0 > bm0) return;

  const ushort* Ab = A + (long)blockIdx.z * sA;
  const ushort* Bb = Bt + (long)blockIdx.z * sB;

  __shared__ uint4 lds_v[131072 / 16];
  char* lds = (char*)lds_v;

  const int tid  = threadIdx.x;
  const int lane = tid & 63;
  const int wave = tid >> 6;       // 8 waves: 2(M) x 4(N)
  const int wr   = wave >> 2;
  const int wc   = wave & 3;
  const int fr   = lane & 15;
  const int fg   = lane >> 4;

  const int nk = K >> 6;

  f32x4 acc[8][4];
#pragma unroll
  for (int i = 0; i < 8; ++i)
#pragma unroll
    for (int j = 0; j < 4; ++j) acc[i][j] = (f32x4){0.f, 0.f, 0.f, 0.f};

  auto STAGE = [&](int tt, int h) {
    if (tt >= nk) return;
    const int isB = h & 1, kh = h >> 1;
    const ushort* G = isB ? Bb : Ab;
    const int r0 = isB ? bn0 : bm0;
    char* slab = lds + ((tt & 1) * 65536 + isB * 32768 + kh * 16384);
#pragma unroll
    for (int u = 0; u < 2; ++u) {
      int s = u * 512 + tid;
      int row = s >> 2;
      int cc = (s & 3) ^ ((row >> 1) & 3);
      gload_lds16(G + (long)(r0 + row) * K + tt * 64 + kh * 32 + cc * 8,
                  (ushort*)(slab + s * 16));
    }
  };

  short8 a[4], b[4];
  auto READA = [&](int cur, int kh, int mh) {
    char* slab = lds + (cur * 65536 + kh * 16384);
#pragma unroll
    for (int i = 0; i < 4; ++i) {
      int row = wr * 128 + (mh * 4 + i) * 16 + fr;
      int cc = fg ^ ((row >> 1) & 3);
      a[i] = *(const short8*)(slab + row * 64 + cc * 16);
    }
  };
  auto READB = [&](int cur, int kh) {
    char* slab = lds + (cur * 65536 + 32768 + kh * 16384);
#pragma unroll
    for (int j = 0; j < 4; ++j) {
      int row = wc * 64 + j * 16 + fr;
      int cc = fg ^ ((row >> 1) & 3);
      b[j] = *(const short8*)(slab + row * 64 + cc * 16);
    }
  };
  auto MM = [&](int mh) {
#pragma unroll
    for (int i = 0; i < 4; ++i)
#pragma unroll
      for (int j = 0; j < 4; ++j)
        acc[mh * 4 + i][j] =
            __builtin_amdgcn_mfma_f32_16x16x32_bf16(a[i], b[j], acc[mh * 4 + i][j], 0, 0, 0);
  };

  STAGE(0, 0); STAGE(0, 1); STAGE(0, 2); STAGE(0, 3);
  STAGE(1, 0); STAGE(1, 1);
  WAITV8();
  SBAR();

  for (int t = 0; t < nk; ++t) {
    const int cur = t & 1;
    READA(cur, 0, 0); READB(cur, 0);
    STAGE(t + 1, 2);
    SBAR(); WAITL0();
    __builtin_amdgcn_s_setprio(1); MM(0); __builtin_amdgcn_s_setprio(0);
    SBAR();
    READA(cur, 0, 1);
    STAGE(t + 1, 3);
    if (t + 1 < nk) { WAITV8(); } else { WAITV0(); }
    SBAR(); WAITL0();
    __builtin_amdgcn_s_setprio(1); MM(1); __builtin_amdgcn_s_setprio(0);
    SBAR();
    READA(cur, 1, 0); READB(cur, 1);
    STAGE(t + 2, 0);
    SBAR(); WAITL0();
    __builtin_amdgcn_s_setprio(1); MM(0); __builtin_amdgcn_s_setprio(0);
    SBAR();
    READA(cur, 1, 1);
    STAGE(t + 2, 1);
    if (t + 2 < nk)      { WAITV8(); }
    else if (t + 1 < nk) { WAITV4(); }
    SBAR(); WAITL0();
    __builtin_amdgcn_s_setprio(1); MM(1); __builtin_amdgcn_s_setprio(0);
    SBAR();
  }

  ushort* Cb = C + (long)blockIdx.z * sC;
#pragma unroll
  for (int mi = 0; mi < 8; ++mi)
#pragma unroll
    for (int j = 0; j < 4; ++j)
#pragma unroll
      for (int r = 0; r < 4; ++r) {
        int row = bm0 + wr * 128 + mi * 16 + fg * 4 + r;
        int col = bn0 + wc * 64 + j * 16 + fr;
        Cb[(long)row * Nn + col] = f2bf(acc[mi][j][r] * alpha);
      }
}

// ---------------- old 128^2 bf16 GEMM (PV with causal k-limit) ----------------
template <int CMODE, int KMODE>
__global__ __launch_bounds__(256) void gemm_bt(
    const ushort* __restrict__ A, const ushort* __restrict__ Bt, void* __restrict__ C,
    int M, int Nn, int K, long sA, long sB, long sC, float alpha)
{
  const int bm0 = blockIdx.x * BM;
  const int bn0 = blockIdx.y * BN;
  if (KMODE == 2 && bn0 > bm0) return;

  const ushort* Ab = A + (long)blockIdx.z * sA;
  const ushort* Bb = Bt + (long)blockIdx.z * sB;

  int kEnd = K;
  if (KMODE == 1) { int ke = bm0 + BM; kEnd = ke < K ? ke : K; }

  __shared__ ushort As[BM * BK];
  __shared__ ushort Bs[BN * BK];

  const int tid  = threadIdx.x;
  const int lane = tid & 63;
  const int wave = tid >> 6;
  const int wm   = (wave >> 1) * 64;
  const int wn   = (wave & 1) * 64;
  const int fr   = lane & 15;
  const int fg   = lane >> 4;

  f32x4 acc[4][4];
#pragma unroll
  for (int i = 0; i < 4; ++i)
#pragma unroll
    for (int j = 0; j < 4; ++j) acc[i][j] = (f32x4){0.f, 0.f, 0.f, 0.f};

  for (int k0 = 0; k0 < kEnd; k0 += BK) {
#pragma unroll
    for (int it = 0; it < 2; ++it) {
      int s = it * 256 + tid;
      int row = s >> 2;
      int col = (s & 3) * 8;
      gload_lds16(Ab + (long)(bm0 + row) * K + (k0 + col), &As[s * 8]);
      gload_lds16(Bb + (long)(bn0 + row) * K + (k0 + col), &Bs[s * 8]);
    }
    __syncthreads();

    short8 af[4], bfg[4];
#pragma unroll
    for (int i = 0; i < 4; ++i)
      af[i] = *(const short8*)&As[(wm + i * 16 + fr) * BK + fg * 8];
#pragma unroll
    for (int j = 0; j < 4; ++j)
      bfg[j] = *(const short8*)&Bs[(wn + j * 16 + fr) * BK + fg * 8];
#pragma unroll
    for (int i = 0; i < 4; ++i)
#pragma unroll
      for (int j = 0; j < 4; ++j)
        acc[i][j] = __builtin_amdgcn_mfma_f32_16x16x32_bf16(af[i], bfg[j], acc[i][j], 0, 0, 0);
    __syncthreads();
  }

  if (CMODE == 0) {
    ushort* Cb = (ushort*)C + (long)blockIdx.z * sC;
#pragma unroll
    for (int i = 0; i < 4; ++i)
#pragma unroll
      for (int j = 0; j < 4; ++j)
#pragma unroll
        for (int r = 0; r < 4; ++r) {
          int row = bm0 + wm + i * 16 + fg * 4 + r;
          int col = bn0 + wn + j * 16 + fr;
          Cb[(long)row * Nn + col] = f2bf(acc[i][j][r] * alpha);
        }
  } else {
    float* Cb = (float*)C + (long)blockIdx.z * sC;
#pragma unroll
    for (int i = 0; i < 4; ++i)
#pragma unroll
      for (int j = 0; j < 4; ++j)
#pragma unroll
        for (int r = 0; r < 4; ++r) {
          int row = bm0 + wm + i * 16 + fg * 4 + r;
          int col = bn0 + wn + j * 16 + fr;
          Cb[(long)row * Nn + col] = acc[i][j][r] * alpha;
        }
  }
}

// ---------------- bf16 transpose ----------------
__global__ void transpose_bf16(const ushort* __restrict__ in, ushort* __restrict__ out,
                               int rows, int cols) {
  __shared__ ushort t[64][65];
  int c0 = blockIdx.x * 64, r0 = blockIdx.y * 64;
  long base = (long)blockIdx.z * rows * cols;
  int tid = threadIdx.x;
#pragma unroll
  for (int i = 0; i < 16; ++i) {
    int idx = i * 256 + tid, r = idx >> 6, c = idx & 63;
    t[r][c] = in[base + (long)(r0 + r) * cols + c0 + c];
  }
  __syncthreads();
#pragma unroll
  for (int i = 0; i < 16; ++i) {
    int idx = i * 256 + tid, r = idx >> 6, c = idx & 63;
    out[base + (long)(c0 + r) * rows + r0 + c] = t[c][r];
  }
}

// ---------------- column softmax stats over q axis (8 cols/thread, 2-pass) ----------------
// grid (Nq/512, Nq/QCH, B), block 64 threads.  Partials: pM/pZ [b][NQC][Nq].
__global__ void colstats_partial(const ushort* __restrict__ S, float* __restrict__ pM,
                                 float* __restrict__ pZ, int Nq) {
  const int k0 = (blockIdx.x * 64 + threadIdx.x) * 8;
  const int qc = blockIdx.y;
  const int b  = blockIdx.z;
  const int q0 = qc * QCH, q1 = q0 + QCH;
  const long o = ((long)(b * NQC + qc)) * Nq + k0;

  float m[8], z[8];
#pragma unroll
  for (int j = 0; j < 8; ++j) { m[j] = -3.0e38f; z[j] = 0.f; }

  const int qs = q0 > k0 ? q0 : k0;          // causal: only q >= k valid
  if (qs < q1) {
    const ushort* Sb = S + (long)b * Nq * Nq;
    // pass 1: max (8 independent chains)
    for (int q = qs; q < q1; ++q) {
      union { uint4 v; ushort u[8]; } d;
      d.v = *(const uint4*)(Sb + (long)q * Nq + k0);
#pragma unroll
      for (int j = 0; j < 8; ++j) {
        float s = bf2f(d.u[j]);
        m[j] = (q >= k0 + j) ? fmaxf(m[j], s) : m[j];
      }
    }
    // pass 2: sum of exp (L1-resident re-read)
    for (int q = qs; q < q1; ++q) {
      union { uint4 v; ushort u[8]; } d;
      d.v = *(const uint4*)(Sb + (long)q * Nq + k0);
#pragma unroll
      for (int j = 0; j < 8; ++j) {
        float e = __expf(bf2f(d.u[j]) - m[j]);
        z[j] += (q >= k0 + j) ? e : 0.f;
      }
    }
  }
#pragma unroll
  for (int j = 0; j < 8; ++j) { pM[o + j] = m[j]; pZ[o + j] = z[j]; }
}

__global__ void colstats_combine(const float* __restrict__ pM, const float* __restrict__ pZ,
                                 float2* __restrict__ Mz, int Nq) {
  int idx = blockIdx.x * 256 + threadIdx.x;   // b*Nq + k
  int b = idx / Nq, k = idx - b * Nq;
  const float* PM = pM + (long)b * NQC * Nq + k;
  const float* PZ = pZ + (long)b * NQC * Nq + k;
  float M = -3.0e38f;
  for (int c = 0; c < NQC; ++c) M = fmaxf(M, PM[(long)c * Nq]);
  float Z = 0.f;
  for (int c = 0; c < NQC; ++c) Z += PZ[(long)c * Nq] * __expf(PM[(long)c * Nq] - M);
  Mz[idx] = make_float2(M, 1.0f / Z);
}

// ---------------- P = exp(s - M[k]) * rZ[k], over the PV READ SET, in place ------------
// PV (q-tile [t*128,(t+1)*128)) reads k in [0, (t+1)*128): must zero k>q up to
// the q-tile's 128 boundary, not just to q.  Skip only groups beyond that.
__global__ void make_p(ushort* __restrict__ S, const float2* __restrict__ Mz, int Nq) {
  long t = (long)blockIdx.x * 256 + threadIdx.x;
  int kb = (int)(t % (Nq / 8)) * 8;
  long row = t / (Nq / 8);
  int q = (int)(row % Nq);
  int b = (int)(row / Nq);
  int kend = ((q >> 7) + 1) << 7;    // PV k-limit for this row's tile
  if (kb >= kend) return;            // never read downstream
  ushort* Sp = S + row * Nq + kb;
  union { uint4 v; ushort u[8]; } d, o;
  d.v = *(const uint4*)Sp;
  const float2* mz = Mz + (long)b * Nq + kb;
#pragma unroll
  for (int j = 0; j < 8; ++j) {
    float2 m = mz[j];
    float p = (q >= kb + j) ? __expf(bf2f(d.u[j]) - m.x) * m.y : 0.f;
    o.u[j] = f2bf(p);
  }
  *(uint4*)Sp = o.v;
}

// ---------------- launch ----------------
extern "C" void kernel_launch(void* const* d_in, const int* in_sizes, int n_in,
                              void* d_out, int out_size, void* d_ws, size_t ws_size,
                              hipStream_t stream) {
  const float* x  = (const float*)d_in[0];
  const float* Wq = (const float*)d_in[1];
  const float* Wk = (const float*)d_in[2];
  const float* Wv = (const float*)d_in[3];
  float* out = (float*)d_out;

  const int B = 4, N = 2048, D = 1024;
  const long BND = (long)B * N * D;

  char* ws = (char*)d_ws;
  ushort* xb  = (ushort*)ws;                         // [B*N][D] bf16, 16MB
  ushort* Vt  = xb;                                  // aliases xb (dead after K1)
  ushort* Wb  = xb + BND;                            // [3][D][D] bf16
  ushort* QKV = Wb + 3L * D * D;                     // [3][B*N][D]
  ushort* Qb  = QKV;
  ushort* Kb  = QKV + BND;
  ushort* Vb  = QKV + 2 * BND;
  ushort* S   = QKV + 3 * BND;                       // [B][N][N] bf16
  float*  pM  = (float*)(S + (long)B * N * N);       // [B][NQC][N] f32, 2MB
  float*  pZ  = pM + (long)B * NQC * N;              // 2MB
  float2* Mz  = (float2*)(pZ + (long)B * NQC * N);   // [B][N]

  // K0: casts
  cast_f32_bf16<<<(int)(BND / 4 / 256), 256, 0, stream>>>(x, xb, (int)(BND / 4));
  cast_f32_bf16<<<(D * D / 4) / 256, 256, 0, stream>>>(Wq, Wb, D * D / 4);
  cast_f32_bf16<<<(D * D / 4) / 256, 256, 0, stream>>>(Wk, Wb + (long)D * D, D * D / 4);
  cast_f32_bf16<<<(D * D / 4) / 256, 256, 0, stream>>>(Wv, Wb + 2L * D * D, D * D / 4);

  // K1: Q/K/V projections, 256^2 8-phase
  {
    dim3 g(B * N / 256, D / 256, 3);
    gemm256<0><<<g, 512, 0, stream>>>(xb, Wb, QKV, B * N, D, D,
                                      0L, (long)D * D, BND, 1.0f);
  }

  // K2: V -> V^T (xb dead now)
  {
    dim3 g(D / 64, N / 64, B);
    transpose_bf16<<<g, 256, 0, stream>>>(Vb, Vt, N, D);
  }

  // K3: S = Q K^T / 32, lower tiles only, 256^2 8-phase
  {
    dim3 g(N / 256, N / 256, B);
    gemm256<2><<<g, 512, 0, stream>>>(Qb, Kb, S, N, N, D,
                                      (long)N * D, (long)N * D, (long)N * N, 0.03125f);
  }

  // K3b: column (query-axis) softmax stats
  {
    dim3 g(N / 512, N / QCH, B);
    colstats_partial<<<g, 64, 0, stream>>>(S, pM, pZ, N);
    colstats_combine<<<(B * N) / 256, 256, 0, stream>>>(pM, pZ, Mz, N);
  }

  // K4: P in place (PV read set)
  make_p<<<(int)((long)B * N * N / 8 / 256), 256, 0, stream>>>(S, Mz, N);

  // K5: O = P @ V (kEnd = bm0+128 causal limit)
  {
    dim3 g(N / BM, D / BN, B);
    gemm_bt<1, 1><<<g, 256, 0, stream>>>(S, Vt, (void*)out, N, D, N,
                                         (long)N * N, (long)D * N, (long)N * D, 1.0f);
  }
}

// Round 5
// 237.577 us; speedup vs baseline: 1.2839x; 1.0608x over previous
//
#include <hip/hip_runtime.h>
#include <stdint.h>

// CausalSelfAttention, B=4 N=2048 D=1024, softmax over QUERY axis (axis=1).
// Pipeline: cast->bf16 | QKV gemm (256x128 BK=64 3-buf 8-phase) | V transpose
//           | S=QK^T/32 (same kernel, causal tile skip, bf16)
//           | column stats (ILP 8-col/thread) | P=exp(s-M)*rZ (PV-read set)
//           | O = P @ V (same kernel, f32 out, kEnd=bm0+256).

#define QCH 32
#define NQC 64   // N / QCH

typedef __attribute__((ext_vector_type(8))) short short8;   // 8 bf16 = 4 VGPR
typedef __attribute__((ext_vector_type(4))) float f32x4;

static __device__ __forceinline__ ushort f2bf(float f) {
  union { float f; uint32_t u; } v; v.f = f;
  uint32_t r = v.u + 0x7FFFu + ((v.u >> 16) & 1u);   // RNE
  return (ushort)(r >> 16);
}
static __device__ __forceinline__ float bf2f(ushort u) {
  union { uint32_t u; float f; } v; v.u = ((uint32_t)u) << 16;
  return v.f;
}

static __device__ __forceinline__ void gload_lds16(const ushort* g, ushort* l) {
  __builtin_amdgcn_global_load_lds(
      (const __attribute__((address_space(1))) void*)g,
      (__attribute__((address_space(3))) void*)l, 16, 0, 0);
}

#define SBAR()   __builtin_amdgcn_s_barrier()
#define SCHED0() __builtin_amdgcn_sched_barrier(0)
#define WAITL0() do { asm volatile("s_waitcnt lgkmcnt(0)" ::: "memory"); SCHED0(); } while (0)
#define WAITV6() asm volatile("s_waitcnt vmcnt(6)" ::: "memory")
#define WAITV0() asm volatile("s_waitcnt vmcnt(0)" ::: "memory")

// ---------------- casts ----------------
__global__ void cast_f32_bf16(const float* __restrict__ in, ushort* __restrict__ out, int n4) {
  int i = blockIdx.x * blockDim.x + threadIdx.x;
  if (i >= n4) return;
  float4 v = ((const float4*)in)[i];
  ushort4 o;
  o.x = f2bf(v.x); o.y = f2bf(v.y); o.z = f2bf(v.z); o.w = f2bf(v.w);
  ((ushort4*)out)[i] = o;
}

// =====================================================================
// 256(M) x 128(N) / BK=64 / 8-wave / triple-buffer LDS (3 x 48KB = 144KB)
// counted vmcnt(6) (stage t+2 while computing t) + T2 swizzle + T5 setprio.
// C = alpha * A @ Bt^T.  A:[M][K], Bt:[Nn][K], K%64==0, nk>=2.
// CMODE: 0 = bf16 C, 1 = f32 C.
// KMODE: 0 = full K; 1 = kEnd=min(K,bm0+256) (causal PV);
//        2 = skip blocks with bn0 >= bm0+256 (causal S), full K.
// Swizzle: 16B-chunk c of row stored at c ^ (row&7) (involution, both sides).
// Waves: 2x... 8 waves as (wr=wave>>1: 4 x 64 rows) x (wc=wave&1: 2 x 64 cols).
// =====================================================================
template <int CMODE, int KMODE>
__global__ __launch_bounds__(512, 2) void gemm256b(
    const ushort* __restrict__ A, const ushort* __restrict__ Bt, void* __restrict__ C,
    int M, int Nn, int K, long sA, long sB, long sC, float alpha)
{
  const int bm0 = blockIdx.x * 256;
  const int bn0 = blockIdx.y * 128;
  if (KMODE == 2 && bn0 >= bm0 + 256) return;

  const ushort* Ab = A + (long)blockIdx.z * sA;
  const ushort* Bb = Bt + (long)blockIdx.z * sB;

  int kEnd = K;
  if (KMODE == 1) { int ke = bm0 + 256; kEnd = ke < K ? ke : K; }
  const int nk = kEnd >> 6;          // K-tiles of 64 (nk >= 4 for our shapes)

  // per buffer: A[256][64]bf16 = 32KB @ 0, B[128][64]bf16 = 16KB @ 32768
  __shared__ uint4 lds_v[147456 / 16];
  char* lds = (char*)lds_v;

  const int tid  = threadIdx.x;
  const int lane = tid & 63;
  const int wave = tid >> 6;
  const int wr   = wave >> 1;        // 0..3 -> rows wr*64
  const int wc   = wave & 1;         // 0..1 -> cols wc*64
  const int fr   = lane & 15;
  const int fg   = lane >> 4;        // 16B chunk within 32-k half

  f32x4 acc[4][4];
#pragma unroll
  for (int i = 0; i < 4; ++i)
#pragma unroll
    for (int j = 0; j < 4; ++j) acc[i][j] = (f32x4){0.f, 0.f, 0.f, 0.f};

  // row byte-length in LDS = 64 bf16 = 128B = 8 chunks of 16B
  auto STAGE_A = [&](int tt) {       // 4 segs/thread, 2048 segs = 32KB
    if (tt >= nk) return;
    char* slab = lds + (tt % 3) * 49152;
#pragma unroll
    for (int u = 0; u < 4; ++u) {
      int s = u * 512 + tid;
      int row = s >> 3;
      int cc = (s & 7) ^ (row & 7);
      gload_lds16(Ab + (long)(bm0 + row) * K + tt * 64 + cc * 8,
                  (ushort*)(slab + s * 16));
    }
  };
  auto STAGE_B = [&](int tt) {       // 2 segs/thread, 1024 segs = 16KB
    if (tt >= nk) return;
    char* slab = lds + (tt % 3) * 49152 + 32768;
#pragma unroll
    for (int u = 0; u < 2; ++u) {
      int s = u * 512 + tid;
      int row = s >> 3;
      int cc = (s & 7) ^ (row & 7);
      gload_lds16(Bb + (long)(bn0 + row) * K + tt * 64 + cc * 8,
                  (ushort*)(slab + s * 16));
    }
  };

  short8 a[4], b[4];
  auto READA = [&](int cur, int kh) {
    char* slab = lds + cur * 49152;
#pragma unroll
    for (int i = 0; i < 4; ++i) {
      int row = wr * 64 + i * 16 + fr;
      int cc = (kh * 4 + fg) ^ (row & 7);
      a[i] = *(const short8*)(slab + row * 128 + cc * 16);
    }
  };
  auto READB = [&](int cur, int kh) {
    char* slab = lds + cur * 49152 + 32768;
#pragma unroll
    for (int j = 0; j < 4; ++j) {
      int row = wc * 64 + j * 16 + fr;
      int cc = (kh * 4 + fg) ^ (row & 7);
      b[j] = *(const short8*)(slab + row * 128 + cc * 16);
    }
  };
  auto MM = [&]() {
#pragma unroll
    for (int i = 0; i < 4; ++i)
#pragma unroll
      for (int j = 0; j < 4; ++j)
        acc[i][j] = __builtin_amdgcn_mfma_f32_16x16x32_bf16(a[i], b[j], acc[i][j], 0, 0, 0);
  };

  // prologue: stage t0, t1 (12 loads) ; wait oldest 6 (t0)
  STAGE_A(0); STAGE_B(0);
  STAGE_A(1); STAGE_B(1);
  WAITV6();
  SBAR();

  for (int t = 0; t < nk; ++t) {
    const int cur = t % 3;
    // ---- phase 0: kh0 ----
    READA(cur, 0); READB(cur, 0);
    STAGE_A(t + 2);
    SBAR(); WAITL0();
    __builtin_amdgcn_s_setprio(1); MM(); __builtin_amdgcn_s_setprio(0);
    SBAR();
    // ---- phase 1: kh1 ----
    READA(cur, 1); READB(cur, 1);
    STAGE_B(t + 2);
    if (t + 2 < nk)      { WAITV6(); }   // t+1's 6 landed; t+2's 6 in flight
    else if (t + 1 < nk) { WAITV0(); }   // tail: drain t+1
    SBAR(); WAITL0();
    __builtin_amdgcn_s_setprio(1); MM(); __builtin_amdgcn_s_setprio(0);
    SBAR();
  }

  // epilogue: C/D map: col = lane&15, row = (lane>>4)*4 + r
  if (CMODE == 0) {
    ushort* Cb = (ushort*)C + (long)blockIdx.z * sC;
#pragma unroll
    for (int i = 0; i < 4; ++i)
#pragma unroll
      for (int j = 0; j < 4; ++j)
#pragma unroll
        for (int r = 0; r < 4; ++r) {
          int row = bm0 + wr * 64 + i * 16 + fg * 4 + r;
          int col = bn0 + wc * 64 + j * 16 + fr;
          Cb[(long)row * Nn + col] = f2bf(acc[i][j][r] * alpha);
        }
  } else {
    float* Cb = (float*)C + (long)blockIdx.z * sC;
#pragma unroll
    for (int i = 0; i < 4; ++i)
#pragma unroll
      for (int j = 0; j < 4; ++j)
#pragma unroll
        for (int r = 0; r < 4; ++r) {
          int row = bm0 + wr * 64 + i * 16 + fg * 4 + r;
          int col = bn0 + wc * 64 + j * 16 + fr;
          Cb[(long)row * Nn + col] = acc[i][j][r] * alpha;
        }
  }
}

// ---------------- bf16 transpose ----------------
__global__ void transpose_bf16(const ushort* __restrict__ in, ushort* __restrict__ out,
                               int rows, int cols) {
  __shared__ ushort t[64][65];
  int c0 = blockIdx.x * 64, r0 = blockIdx.y * 64;
  long base = (long)blockIdx.z * rows * cols;
  int tid = threadIdx.x;
#pragma unroll
  for (int i = 0; i < 16; ++i) {
    int idx = i * 256 + tid, r = idx >> 6, c = idx & 63;
    t[r][c] = in[base + (long)(r0 + r) * cols + c0 + c];
  }
  __syncthreads();
#pragma unroll
  for (int i = 0; i < 16; ++i) {
    int idx = i * 256 + tid, r = idx >> 6, c = idx & 63;
    out[base + (long)(c0 + r) * rows + r0 + c] = t[c][r];
  }
}

// ---------------- column softmax stats over q axis (8 cols/thread, 2-pass) ----------------
// grid (Nq/512, Nq/QCH, B), block 64 threads.  Partials: pM/pZ [b][NQC][Nq].
__global__ void colstats_partial(const ushort* __restrict__ S, float* __restrict__ pM,
                                 float* __restrict__ pZ, int Nq) {
  const int k0 = (blockIdx.x * 64 + threadIdx.x) * 8;
  const int qc = blockIdx.y;
  const int b  = blockIdx.z;
  const int q0 = qc * QCH, q1 = q0 + QCH;
  const long o = ((long)(b * NQC + qc)) * Nq + k0;

  float m[8], z[8];
#pragma unroll
  for (int j = 0; j < 8; ++j) { m[j] = -3.0e38f; z[j] = 0.f; }

  const int qs = q0 > k0 ? q0 : k0;          // causal: only q >= k valid
  if (qs < q1) {
    const ushort* Sb = S + (long)b * Nq * Nq;
    for (int q = qs; q < q1; ++q) {
      union { uint4 v; ushort u[8]; } d;
      d.v = *(const uint4*)(Sb + (long)q * Nq + k0);
#pragma unroll
      for (int j = 0; j < 8; ++j) {
        float s = bf2f(d.u[j]);
        m[j] = (q >= k0 + j) ? fmaxf(m[j], s) : m[j];
      }
    }
    for (int q = qs; q < q1; ++q) {
      union { uint4 v; ushort u[8]; } d;
      d.v = *(const uint4*)(Sb + (long)q * Nq + k0);
#pragma unroll
      for (int j = 0; j < 8; ++j) {
        float e = __expf(bf2f(d.u[j]) - m[j]);
        z[j] += (q >= k0 + j) ? e : 0.f;
      }
    }
  }
#pragma unroll
  for (int j = 0; j < 8; ++j) { pM[o + j] = m[j]; pZ[o + j] = z[j]; }
}

__global__ void colstats_combine(const float* __restrict__ pM, const float* __restrict__ pZ,
                                 float2* __restrict__ Mz, int Nq) {
  int idx = blockIdx.x * 256 + threadIdx.x;   // b*Nq + k
  int b = idx / Nq, k = idx - b * Nq;
  const float* PM = pM + (long)b * NQC * Nq + k;
  const float* PZ = pZ + (long)b * NQC * Nq + k;
  float M = -3.0e38f;
  for (int c = 0; c < NQC; ++c) M = fmaxf(M, PM[(long)c * Nq]);
  float Z = 0.f;
  for (int c = 0; c < NQC; ++c) Z += PZ[(long)c * Nq] * __expf(PM[(long)c * Nq] - M);
  Mz[idx] = make_float2(M, 1.0f / Z);
}

// ---------------- P = exp(s - M[k]) * rZ[k], over the PV READ SET, in place ------------
// PV (q-tile [t*256,(t+1)*256)) reads k in [0, (t+1)*256): must zero k>q up to
// the q-tile's 256 boundary.  Skip only groups beyond that.
__global__ void make_p(ushort* __restrict__ S, const float2* __restrict__ Mz, int Nq) {
  long t = (long)blockIdx.x * 256 + threadIdx.x;
  int kb = (int)(t % (Nq / 8)) * 8;
  long row = t / (Nq / 8);
  int q = (int)(row % Nq);
  int b = (int)(row / Nq);
  int kend = ((q >> 8) + 1) << 8;    // PV k-limit for this row's 256-tile
  if (kb >= kend) return;            // never read downstream
  ushort* Sp = S + row * Nq + kb;
  union { uint4 v; ushort u[8]; } d, o;
  d.v = *(const uint4*)Sp;
  const float2* mz = Mz + (long)b * Nq + kb;
#pragma unroll
  for (int j = 0; j < 8; ++j) {
    float2 m = mz[j];
    float p = (q >= kb + j) ? __expf(bf2f(d.u[j]) - m.x) * m.y : 0.f;
    o.u[j] = f2bf(p);
  }
  *(uint4*)Sp = o.v;
}

// ---------------- launch ----------------
extern "C" void kernel_launch(void* const* d_in, const int* in_sizes, int n_in,
                              void* d_out, int out_size, void* d_ws, size_t ws_size,
                              hipStream_t stream) {
  const float* x  = (const float*)d_in[0];
  const float* Wq = (const float*)d_in[1];
  const float* Wk = (const float*)d_in[2];
  const float* Wv = (const float*)d_in[3];
  float* out = (float*)d_out;

  const int B = 4, N = 2048, D = 1024;
  const long BND = (long)B * N * D;

  char* ws = (char*)d_ws;
  ushort* xb  = (ushort*)ws;                         // [B*N][D] bf16, 16MB
  ushort* Vt  = xb;                                  // aliases xb (dead after K1)
  ushort* Wb  = xb + BND;                            // [3][D][D] bf16
  ushort* QKV = Wb + 3L * D * D;                     // [3][B*N][D]
  ushort* Qb  = QKV;
  ushort* Kb  = QKV + BND;
  ushort* Vb  = QKV + 2 * BND;
  ushort* S   = QKV + 3 * BND;                       // [B][N][N] bf16
  float*  pM  = (float*)(S + (long)B * N * N);       // [B][NQC][N] f32, 2MB
  float*  pZ  = pM + (long)B * NQC * N;              // 2MB
  float2* Mz  = (float2*)(pZ + (long)B * NQC * N);   // [B][N]

  // K0: casts
  cast_f32_bf16<<<(int)(BND / 4 / 256), 256, 0, stream>>>(x, xb, (int)(BND / 4));
  cast_f32_bf16<<<(D * D / 4) / 256, 256, 0, stream>>>(Wq, Wb, D * D / 4);
  cast_f32_bf16<<<(D * D / 4) / 256, 256, 0, stream>>>(Wk, Wb + (long)D * D, D * D / 4);
  cast_f32_bf16<<<(D * D / 4) / 256, 256, 0, stream>>>(Wv, Wb + 2L * D * D, D * D / 4);

  // K1: Q/K/V projections, 256x128 tiles -> 768 blocks = 3/CU exact
  {
    dim3 g(B * N / 256, D / 128, 3);
    gemm256b<0, 0><<<g, 512, 0, stream>>>(xb, Wb, (void*)QKV, B * N, D, D,
                                          0L, (long)D * D, BND, 1.0f);
  }

  // K2: V -> V^T (xb dead now)
  {
    dim3 g(D / 64, N / 64, B);
    transpose_bf16<<<g, 256, 0, stream>>>(Vb, Vt, N, D);
  }

  // K3: S = Q K^T / 32, tiles with bn0 < bm0+256 only
  {
    dim3 g(N / 256, N / 128, B);
    gemm256b<0, 2><<<g, 512, 0, stream>>>(Qb, Kb, (void*)S, N, N, D,
                                          (long)N * D, (long)N * D, (long)N * N, 0.03125f);
  }

  // K3b: column (query-axis) softmax stats
  {
    dim3 g(N / 512, N / QCH, B);
    colstats_partial<<<g, 64, 0, stream>>>(S, pM, pZ, N);
    colstats_combine<<<(B * N) / 256, 256, 0, stream>>>(pM, pZ, Mz, N);
  }

  // K4: P in place (PV read set, 256-tile boundary)
  make_p<<<(int)((long)B * N * N / 8 / 256), 256, 0, stream>>>(S, Mz, N);

  // K5: O = P @ V  (f32 out, kEnd = bm0+256), 256 blocks = 1/CU exact
  {
    dim3 g(N / 256, D / 128, B);
    gemm256b<1, 1><<<g, 512, 0, stream>>>(S, Vt, (void*)out, N, D, N,
                                          (long)N * N, (long)D * N, (long)N * D, 1.0f);
  }
}